// Round 5
// baseline (464.192 us; speedup 1.0000x reference)
//
#include <hip/hip_runtime.h>

#define N_NODES 8192
#define FDIM 128
#define NEG_SLOPE 0.2f
#define SEG 512   // per-wave neighbor capacity (mean ~102, ~40 sigma headroom)

// order-preserving float->uint key for atomicMax on signed floats
__device__ inline unsigned fkey(float x) {
  unsigned b = __float_as_uint(x);
  return (b & 0x80000000u) ? ~b : (b | 0x80000000u);
}

// ---------------- Kernel A: Wh = h @ W.T + s1/s2 + s2max + colsum S --------
// 256 blocks x 256 thr; block = 32 rows x 128 cols; thread = 4 rows x 4 cols.
__global__ __launch_bounds__(256) void wh_fused_kernel(
    const float* __restrict__ h, const float* __restrict__ W,
    const float* __restrict__ a, float* __restrict__ Wh,
    float* __restrict__ s1g, float* __restrict__ s2g,
    float* __restrict__ S, unsigned* __restrict__ s2max_key) {
  __shared__ float Wt[FDIM * 132];   // Wt[k*132+o] = W[o][k]
  __shared__ float rows[32 * 132];   // rows[r*132+k]; reused as colsum scratch
  const int t = threadIdx.x;
  const int base = blockIdx.x * 32;
  for (int it = 0; it < 64; ++it) {
    int idx = t + 256 * it;          // idx = o*128+k
    int o = idx >> 7, k = idx & 127;
    Wt[k * 132 + o] = W[idx];
  }
  for (int it = 0; it < 16; ++it) {
    int idx = t + 256 * it;          // idx = r*128+col
    int r = idx >> 7, col = idx & 127;
    rows[r * 132 + col] = h[(size_t)base * FDIM + idx];
  }
  __syncthreads();
  const int c4 = (t & 31) * 4;
  const int g = t >> 5;
  float acc[4][4];
#pragma unroll
  for (int rr = 0; rr < 4; ++rr)
#pragma unroll
    for (int cc = 0; cc < 4; ++cc) acc[rr][cc] = 0.f;
  for (int k = 0; k < FDIM; ++k) {
    float4 wv = *(const float4*)&Wt[k * 132 + c4];
    float rv[4];
#pragma unroll
    for (int rr = 0; rr < 4; ++rr) rv[rr] = rows[(4 * g + rr) * 132 + k];
#pragma unroll
    for (int rr = 0; rr < 4; ++rr) {
      acc[rr][0] += rv[rr] * wv.x;
      acc[rr][1] += rv[rr] * wv.y;
      acc[rr][2] += rv[rr] * wv.z;
      acc[rr][3] += rv[rr] * wv.w;
    }
  }
#pragma unroll
  for (int rr = 0; rr < 4; ++rr) {
    int r = base + 4 * g + rr;
    *(float4*)&Wh[(size_t)r * FDIM + c4] =
        make_float4(acc[rr][0], acc[rr][1], acc[rr][2], acc[rr][3]);
  }
  // ---- s1/s2 epilogue (register partials + width-32 shfl reduce) ----
  {
    float4 a1c = *(const float4*)&a[c4];
    float4 a2c = *(const float4*)&a[FDIM + c4];
    float p1[4], p2[4];
#pragma unroll
    for (int rr = 0; rr < 4; ++rr) {
      p1[rr] = acc[rr][0] * a1c.x + acc[rr][1] * a1c.y +
               acc[rr][2] * a1c.z + acc[rr][3] * a1c.w;
      p2[rr] = acc[rr][0] * a2c.x + acc[rr][1] * a2c.y +
               acc[rr][2] * a2c.z + acc[rr][3] * a2c.w;
    }
#pragma unroll
    for (int rr = 0; rr < 4; ++rr)
      for (int off = 16; off; off >>= 1) {
        p1[rr] += __shfl_down(p1[rr], off, 32);
        p2[rr] += __shfl_down(p2[rr], off, 32);
      }
    if ((t & 31) == 0) {
      unsigned kmax = 0;
#pragma unroll
      for (int rr = 0; rr < 4; ++rr) {
        int r = base + 4 * g + rr;
        s1g[r] = p1[rr];
        s2g[r] = p2[rr];
        unsigned kk = fkey(p2[rr]);
        kmax = kk > kmax ? kk : kmax;
      }
      atomicMax(s2max_key, kmax);
    }
  }
  // ---- colsum epilogue ----
  __syncthreads();                   // all waves done reading rows[]
  float4 cs = make_float4(acc[0][0] + acc[1][0] + acc[2][0] + acc[3][0],
                          acc[0][1] + acc[1][1] + acc[2][1] + acc[3][1],
                          acc[0][2] + acc[1][2] + acc[2][2] + acc[3][2],
                          acc[0][3] + acc[1][3] + acc[2][3] + acc[3][3]);
  *(float4*)&rows[g * FDIM + c4] = cs;
  __syncthreads();
  if (t < FDIM) {
    float s = 0.f;
#pragma unroll
    for (int gg = 0; gg < 8; ++gg) s += rows[gg * FDIM + t];
    atomicAdd(&S[t], s);
  }
}

// ---------------- Kernel B: fused scan+softmax+gather, barrier-free --------
// one block (4 waves) per row i. m_i = max(0, lrelu(s1_i + s2max)) is an
// upper bound on all e_ij (lrelu monotone) -> softmax shift-invariance makes
// it exact. Each wave: per 256-col chunk, compact (p-em, j) with exp fused,
// then drain-gather pending pairs in 8-pair quanta (4 float4 loads in
// flight). Scan (HBM) and gather (L2) overlap within every wave; the only
// barrier is the final cross-wave sum.
__global__ __launch_bounds__(256) void gat_row_kernel(
    const float* __restrict__ adj, const float* __restrict__ Wh,
    const float* __restrict__ s1, const float* __restrict__ s2,
    const unsigned* __restrict__ s2max_key, const float* __restrict__ S,
    float* __restrict__ out) {
  const int i = blockIdx.x;
  const int t = threadIdx.x;
  const int lane = t & 63;
  const int wave = t >> 6;
  __shared__ float2 pairs[4 * SEG];  // (p - em, j bits)
  __shared__ int counts[4];
  __shared__ float red2[4];
  __shared__ float fpart[4][FDIM];

  const float s1i = s1[i];
  // decode order-preserving key -> s2max
  unsigned kk = *s2max_key;
  unsigned bb = (kk & 0x80000000u) ? (kk ^ 0x80000000u) : ~kk;
  float pm = s1i + __uint_as_float(bb);
  pm = pm > 0.f ? pm : NEG_SLOPE * pm;
  const float m = fmaxf(pm, 0.f);
  const float em = __expf(-m);

  const float4* __restrict__ arow = (const float4*)(adj + (size_t)i * N_NODES);
  const float4* __restrict__ s2v = (const float4*)s2;
  float2* __restrict__ mypairs = pairs + wave * SEG;
  const unsigned long long lmask = (1ull << lane) - 1ull;
  const int half = lane >> 5, lq = lane & 31;
  const float4* __restrict__ Wh4 = (const float4*)Wh;

  int cbase = 0, drained = 0;
  float lsum = 0.f;
  float ax = 0.f, ay = 0.f, az = 0.f, aw = 0.f;

  float4 av = arow[t], sv = s2v[t];
#pragma unroll
  for (int it = 0; it < 8; ++it) {
    float4 avn, svn;
    if (it < 7) {
      avn = arow[(it + 1) * 256 + t];
      svn = s2v[(it + 1) * 256 + t];
    }
    const int j4 = it * 256 + t;
    float vv[4] = {av.x, av.y, av.z, av.w};
    float ss[4] = {sv.x, sv.y, sv.z, sv.w};
#pragma unroll
    for (int c = 0; c < 4; ++c) {
      bool pred = (vv[c] != 0.f);
      float e = s1i + ss[c];
      e = e > 0.f ? e : NEG_SLOPE * e;
      float p = __expf(e - m);
      unsigned long long b = __ballot(pred);
      if (pred) {
        int pos = cbase + (int)__popcll(b & lmask);
        if (pos < SEG)
          mypairs[pos] = make_float2(p - em, __int_as_float(j4 * 4 + c));
      }
      lsum += pred ? p : 0.f;
      cbase += (int)__popcll(b);
    }
    av = avn; sv = svn;
    // ---- drain pending pairs, 8 at a time (4 loads in flight) ----
    int cc = cbase < SEG ? cbase : SEG;
    while (drained + 8 <= cc) {
      float2 pr0 = mypairs[drained + half];
      float2 pr1 = mypairs[drained + 2 + half];
      float2 pr2 = mypairs[drained + 4 + half];
      float2 pr3 = mypairs[drained + 6 + half];
      float4 v0 = Wh4[((size_t)__float_as_int(pr0.y) << 5) + lq];
      float4 v1 = Wh4[((size_t)__float_as_int(pr1.y) << 5) + lq];
      float4 v2 = Wh4[((size_t)__float_as_int(pr2.y) << 5) + lq];
      float4 v3 = Wh4[((size_t)__float_as_int(pr3.y) << 5) + lq];
      ax += pr0.x * v0.x + pr1.x * v1.x + pr2.x * v2.x + pr3.x * v3.x;
      ay += pr0.x * v0.y + pr1.x * v1.y + pr2.x * v2.y + pr3.x * v3.y;
      az += pr0.x * v0.z + pr1.x * v1.z + pr2.x * v2.z + pr3.x * v3.z;
      aw += pr0.x * v0.w + pr1.x * v1.w + pr2.x * v2.w + pr3.x * v3.w;
      drained += 8;
    }
  }
  // ---- final drain (masked 2-pair steps) ----
  {
    int cc = cbase < SEG ? cbase : SEG;
    while (drained < cc) {
      int p0 = drained + half;
      bool ok = p0 < cc;
      float2 pr = mypairs[ok ? p0 : 0];
      float4 v = Wh4[((size_t)__float_as_int(pr.y) << 5) + lq];
      float w = ok ? pr.x : 0.f;
      ax += w * v.x; ay += w * v.y; az += w * v.z; aw += w * v.w;
      drained += 2;
    }
  }
  // combine odd/even halves (same features, disjoint pair subsets)
  ax += __shfl_down(ax, 32);
  ay += __shfl_down(ay, 32);
  az += __shfl_down(az, 32);
  aw += __shfl_down(aw, 32);
  for (int off = 32; off; off >>= 1) lsum += __shfl_down(lsum, off);
  if (lane == 0) {
    red2[wave] = lsum;
    counts[wave] = cbase < SEG ? cbase : SEG;
  }
  if (lane < 32)
    *(float4*)&fpart[wave][4 * lq] = make_float4(ax, ay, az, aw);
  __syncthreads();
  if (t < FDIM) {
    int cnt = counts[0] + counts[1] + counts[2] + counts[3];
    float l = red2[0] + red2[1] + red2[2] + red2[3]
              + (float)(N_NODES - cnt) * em;
    float o = (fpart[0][t] + fpart[1][t] + fpart[2][t] + fpart[3][t]
               + em * S[t]) / l;
    out[(size_t)i * FDIM + t] = o;
  }
}

extern "C" void kernel_launch(void* const* d_in, const int* in_sizes, int n_in,
                              void* d_out, int out_size, void* d_ws, size_t ws_size,
                              hipStream_t stream) {
  const float* h   = (const float*)d_in[0];
  const float* adj = (const float*)d_in[1];
  const float* W   = (const float*)d_in[2];
  const float* a   = (const float*)d_in[3];
  float* out = (float*)d_out;
  // workspace (fp32): Wh[N*F] | s1[N] | s2[N] | S[F] | s2max_key (uint)
  float* Wh = (float*)d_ws;
  float* s1 = Wh + (size_t)N_NODES * FDIM;
  float* s2 = s1 + N_NODES;
  float* S  = s2 + N_NODES;
  unsigned* s2max_key = (unsigned*)(S + FDIM);

  hipMemsetAsync(S, 0, FDIM * sizeof(float) + sizeof(unsigned), stream);
  hipLaunchKernelGGL(wh_fused_kernel, dim3(N_NODES / 32), dim3(256), 0, stream,
                     h, W, a, Wh, s1, s2, S, s2max_key);
  hipLaunchKernelGGL(gat_row_kernel, dim3(N_NODES), dim3(256), 0, stream,
                     adj, Wh, s1, s2, s2max_key, S, out);
}